// Round 5
// baseline (3084.694 us; speedup 1.0000x reference)
//
#include <hip/hip_runtime.h>
#include <hip/hip_bf16.h>
#include <cmath>

#define NB   16
#define LL   1024
#define DD   512
#define NCLS 64

// ---------------------------------------------- fused embed-gather + proj GEMM
// C[m][n] = b1[n] + b2[n] + sum_k emb[x[m]][k] * W[n][k]   (M=16384, N=K=512)
__global__ __launch_bounds__(256) void k_gemm_embed(
    const int* __restrict__ x, const float* __restrict__ emb,
    const float* __restrict__ W, const float* __restrict__ b1,
    const float* __restrict__ b2, float* __restrict__ C)
{
  __shared__ __align__(16) float As[32][68];  // [k][m], +4 pad
  __shared__ __align__(16) float Ws[32][68];  // [k][n]
  const int tid = threadIdx.x;
  const int n0 = (blockIdx.x & 7) * 64;
  const int m0 = (blockIdx.x >> 3) * 64;
  const int tm = tid & 15, tn = tid >> 4;
  float acc[4][4] = {};

  const int f0 = tid * 2, f1 = tid * 2 + 1;
  const int r0 = f0 >> 3, q0 = f0 & 7;
  const int r1 = f1 >> 3, q1 = f1 & 7;
  const long arow0 = (long)x[m0 + r0] * DD;
  const long arow1 = (long)x[m0 + r1] * DD;
  const long wrow0 = (long)(n0 + r0) * DD;
  const long wrow1 = (long)(n0 + r1) * DD;

  for (int k0 = 0; k0 < DD; k0 += 32) {
    float4 va = *(const float4*)(emb + arow0 + k0 + q0 * 4);
    float4 vb = *(const float4*)(emb + arow1 + k0 + q1 * 4);
    float4 wa = *(const float4*)(W + wrow0 + k0 + q0 * 4);
    float4 wb = *(const float4*)(W + wrow1 + k0 + q1 * 4);
    __syncthreads();
    As[q0*4+0][r0]=va.x; As[q0*4+1][r0]=va.y; As[q0*4+2][r0]=va.z; As[q0*4+3][r0]=va.w;
    As[q1*4+0][r1]=vb.x; As[q1*4+1][r1]=vb.y; As[q1*4+2][r1]=vb.z; As[q1*4+3][r1]=vb.w;
    Ws[q0*4+0][r0]=wa.x; Ws[q0*4+1][r0]=wa.y; Ws[q0*4+2][r0]=wa.z; Ws[q0*4+3][r0]=wa.w;
    Ws[q1*4+0][r1]=wb.x; Ws[q1*4+1][r1]=wb.y; Ws[q1*4+2][r1]=wb.z; Ws[q1*4+3][r1]=wb.w;
    __syncthreads();
    #pragma unroll
    for (int kk = 0; kk < 32; ++kk) {
      float4 a = *(const float4*)&As[kk][tm * 4];
      float4 w = *(const float4*)&Ws[kk][tn * 4];
      acc[0][0]+=a.x*w.x; acc[0][1]+=a.x*w.y; acc[0][2]+=a.x*w.z; acc[0][3]+=a.x*w.w;
      acc[1][0]+=a.y*w.x; acc[1][1]+=a.y*w.y; acc[1][2]+=a.y*w.z; acc[1][3]+=a.y*w.w;
      acc[2][0]+=a.z*w.x; acc[2][1]+=a.z*w.y; acc[2][2]+=a.z*w.z; acc[2][3]+=a.z*w.w;
      acc[3][0]+=a.w*w.x; acc[3][1]+=a.w*w.y; acc[3][2]+=a.w*w.z; acc[3][3]+=a.w*w.w;
    }
  }
  float bj[4];
  #pragma unroll
  for (int j = 0; j < 4; ++j)
    bj[j] = b1[n0 + tn * 4 + j] + b2[n0 + tn * 4 + j];
  #pragma unroll
  for (int i = 0; i < 4; ++i) {
    const int m = m0 + tm * 4 + i;
    float4 o = { acc[i][0]+bj[0], acc[i][1]+bj[1], acc[i][2]+bj[2], acc[i][3]+bj[3] };
    *(float4*)(C + (long)m * DD + n0 + tn * 4) = o;
  }
}

// ---------------------------------------------------------------- scan helpers
__device__ __forceinline__ float wave_red8(float y) {
  y += __int_as_float(__builtin_amdgcn_ds_swizzle(__float_as_int(y), 0x041F));
  y += __int_as_float(__builtin_amdgcn_ds_swizzle(__float_as_int(y), 0x081F));
  y += __int_as_float(__builtin_amdgcn_ds_swizzle(__float_as_int(y), 0x101F));
  return y;
}
__device__ __forceinline__ unsigned long long ald64(const float* p) {
  return __hip_atomic_load((const unsigned long long*)p, __ATOMIC_RELAXED,
                           __HIP_MEMORY_SCOPE_AGENT);
}
__device__ __forceinline__ void enc_st(float* p, float v) {
  __hip_atomic_store(p, v + 2.0f, __ATOMIC_RELAXED, __HIP_MEMORY_SCOPE_AGENT);
}
__device__ __forceinline__ float u64lo(unsigned long long u) {
  return __uint_as_float((unsigned)u);
}
__device__ __forceinline__ float u64hi(unsigned long long u) {
  return __uint_as_float((unsigned)(u >> 32));
}
__device__ __forceinline__ float bl(unsigned u) { return __uint_as_float(u << 16); }
__device__ __forceinline__ float bh(unsigned u) { return __uint_as_float(u & 0xffff0000u); }
__device__ __forceinline__ unsigned short b16(float a) {
  __hip_bfloat16 h = __float2bfloat16(a);
  return *reinterpret_cast<unsigned short*>(&h);
}
__device__ __forceinline__ unsigned pk(float a, float b) {
  return (unsigned)b16(a) | ((unsigned)b16(b) << 16);
}
__device__ __forceinline__ float fast_tanh(float x) {
  float e = __expf(2.0f * x);
  return 1.0f - 2.0f / (e + 1.0f);
}
// 64-length dot: thread-tiled bf16x2 weights (uint4 at Wp[t4*128+ctid]) vs fp32 h slice
__device__ __forceinline__ float dot64_bf16(const uint4* Wp, int ctid, const float* hslice) {
  const float4* hp = (const float4*)hslice;
  float y0 = 0.f, y1 = 0.f, y2 = 0.f, y3 = 0.f;
  #pragma unroll
  for (int t4 = 0; t4 < 8; ++t4) {
    uint4 u = Wp[t4 * 128 + ctid];
    float4 ha = hp[2 * t4], hb = hp[2 * t4 + 1];
    y0 += bl(u.x) * ha.x; y1 += bh(u.x) * ha.y;
    y2 += bl(u.y) * ha.z; y3 += bh(u.y) * ha.w;
    y0 += bl(u.z) * hb.x; y1 += bh(u.z) * hb.y;
    y2 += bl(u.w) * hb.z; y3 += bh(u.w) * hb.w;
  }
  return (y0 + y1) + (y2 + y3);
}

// ------------------------------------------------- persistent 2-layer RNN scan
// 256 WGs = 32 row-groups (16 rows) x 8 batch-pairs (batches bp, bp+8).
// w1 (Whh1, critical) = 64 fp32/thread in regs (matches compiler's demonstrated
// 116-reg appetite). w2/w3 (layer 2) = bf16x2 thread-tiled LDS (32 KB) -> zero
// RA dependence, conflict-free ds_read_b128. Handshake: data-poll (h+2) with
// probe-early/check-late so IF$ latency hides under M3/M2 compute.
__global__ __attribute__((amdgpu_flat_work_group_size(256, 256)))
__attribute__((amdgpu_waves_per_eu(1, 1)))
void k_scan(
    const float* __restrict__ W_ih, const float* __restrict__ W_hh,
    const float* __restrict__ b_ih, const float* __restrict__ b_hh,
    float* __restrict__ Bbuf,   // in: xproj layer1 -> h1+2 (in-place)
    float* __restrict__ Abuf)   // h2+2 (O2, encoded)
{
  const int g = blockIdx.x;
  const int bp = g & 7;            // batch pair: batches bp, bp+8 (XCD-grouped)
  const int rg = g >> 3;           // row group [0,32): rows rg*16..+15
  const int tid = threadIdx.x;
  const int bb = tid >> 7;         // which batch of the pair
  const int rl = (tid >> 3) & 15;  // row within group
  const int part = tid & 7;        // k-part (64 floats)
  const int ctid = tid & 127;      // weight-tile index (shared across bb)
  const int row = rg * 16 + rl;
  const int bmy = bp + 8 * bb;     // my batch
  const bool leader = (part == 0);

  __shared__ __align__(16) float hS1[2][2][8 * 68];  // [buf][bb] staged h1
  __shared__ __align__(16) float hS2[2][2][8 * 68];  // [buf][bb] staged h2
  __shared__ uint4 W2P[8 * 128];                     // Wih l1, bf16x2 tiled (16 KB)
  __shared__ uint4 W3P[8 * 128];                     // Whh l1, bf16x2 tiled (16 KB)

  // ---- w1 (critical path) into registers ----
  float w1[64];
  {
    const volatile float* p1 = W_hh + (long)row * DD + part * 64;
    #pragma unroll
    for (int q = 0; q < 64; ++q) w1[q] = p1[q];
  }
  // ---- build bf16-packed thread-tiled layer-2 weights in LDS (tid<128) ----
  if (tid < 128) {
    const int brow = rg * 16 + (ctid >> 3);
    const int bpart = ctid & 7;
    const float* p2 = W_ih + (long)DD * DD + (long)brow * DD + bpart * 64;
    const float* p3 = W_hh + (long)DD * DD + (long)brow * DD + bpart * 64;
    for (int t4 = 0; t4 < 8; ++t4) {
      uint4 u2, u3;
      u2.x = pk(p2[t4*8+0], p2[t4*8+1]); u2.y = pk(p2[t4*8+2], p2[t4*8+3]);
      u2.z = pk(p2[t4*8+4], p2[t4*8+5]); u2.w = pk(p2[t4*8+6], p2[t4*8+7]);
      u3.x = pk(p3[t4*8+0], p3[t4*8+1]); u3.y = pk(p3[t4*8+2], p3[t4*8+3]);
      u3.z = pk(p3[t4*8+4], p3[t4*8+5]); u3.w = pk(p3[t4*8+6], p3[t4*8+7]);
      W2P[t4 * 128 + ctid] = u2;
      W3P[t4 * 128 + ctid] = u3;
    }
  }
  const float bias2 = b_ih[DD + row] + b_hh[DD + row];
  float xin2_d1 = 0.f;   // xin2(tau-1) after step tau's M2

  float* Bb = Bbuf + (long)bmy * LL * DD;
  float* Ab = Abuf + (long)bmy * LL * DD;

  // staging role: sel 0/1 -> h1 of batch bp/bp+8 ; sel 2/3 -> h2 of bp/bp+8
  const int sel = tid >> 6;
  const int tl = tid & 63;
  float* psrcbase = ((sel < 2) ? Bbuf : Abuf) + (long)(bp + (sel & 1) * 8) * LL * DD;
  const int ldsw = (tl >> 3) * 68 + (tl & 7) * 8;   // dest word in 68-padded slice

  float xpv = 0.f;
  if (leader) xpv = Bb[row];   // xproj(0); plain load (pre-scan data)
  __syncthreads();             // weights LDS ready

  for (int tau = 0; tau <= LL + 1; ++tau) {
    const int cur = tau & 1, nxt = cur ^ 1;

    // ---- M1: h1(tau) = tanh(xproj + w1 . h1(tau-1)) — critical chain ----
    if (tau < LL) {
      float y = 0.f;
      if (tau >= 1) {
        const float4* hp = (const float4*)&hS1[cur][bb][part * 68];
        float y0 = 0.f, y1 = 0.f, y2 = 0.f, y3 = 0.f;
        #pragma unroll
        for (int q = 0; q < 16; ++q) {
          float4 h4 = hp[q];
          y0 += w1[4*q+0] * h4.x; y1 += w1[4*q+1] * h4.y;
          y2 += w1[4*q+2] * h4.z; y3 += w1[4*q+3] * h4.w;
        }
        y = (y0 + y1) + (y2 + y3);
      }
      y = wave_red8(y);
      if (leader) enc_st(Bb + (long)tau * DD + row, fast_tanh(xpv + y));
    }

    // ---- issue probes for next step's staging (check after M3/M2) ----
    const bool need = (sel < 2) ? (tau < LL) : (tau >= 2 && tau <= LL);
    const float* src = psrcbase + (long)((sel < 2) ? tau : (tau - 2) < 0 ? 0 : (tau - 2)) * DD + tl * 8;
    unsigned long long u0 = 0, u1 = 0, u2 = 0, u3 = 0;
    if (need) { u0 = ald64(src); u1 = ald64(src + 2); u2 = ald64(src + 4); u3 = ald64(src + 6); }
    if (leader && tau + 1 < LL) xpv = Bb[(long)(tau + 1) * DD + row];  // prefetch xproj

    // ---- M3: h2(tau-2) = tanh(xin2(tau-2) + w3 . h2(tau-3)) ----
    if (tau >= 2) {
      float y = 0.f;
      if (tau >= 3) y = dot64_bf16(W3P, ctid, &hS2[cur][bb][part * 68]);
      y = wave_red8(y);
      if (leader) enc_st(Ab + (long)(tau - 2) * DD + row, fast_tanh(xin2_d1 + y));
    }
    // ---- M2: xin2(tau-1) = w2 . h1(tau-1) + bias2 (after M3 consumed old) ----
    if (tau >= 1 && tau <= LL) {
      float y = dot64_bf16(W2P, ctid, &hS1[cur][bb][part * 68]);
      y = wave_red8(y);
      xin2_d1 = y + bias2;
    }

    // ---- check probes, spin if needed, stage into next buffer ----
    if (need) {
      for (;;) {
        float a0 = u64lo(u0), a1 = u64hi(u0), c0 = u64lo(u1), c1 = u64hi(u1);
        float d0 = u64lo(u2), d1 = u64hi(u2), e0 = u64lo(u3), e1 = u64hi(u3);
        float mn = fminf(fminf(fminf(a0, a1), fminf(c0, c1)),
                         fminf(fminf(d0, d1), fminf(e0, e1)));
        if (mn > 1.0f) {
          float* dst = ((sel < 2) ? &hS1[nxt][sel & 1][0] : &hS2[nxt][sel & 1][0]) + ldsw;
          ((float4*)dst)[0] = make_float4(a0 - 2.f, a1 - 2.f, c0 - 2.f, c1 - 2.f);
          ((float4*)dst)[1] = make_float4(d0 - 2.f, d1 - 2.f, e0 - 2.f, e1 - 2.f);
          break;
        }
        u0 = ald64(src); u1 = ald64(src + 2); u2 = ald64(src + 4); u3 = ald64(src + 6);
      }
    }
    __syncthreads();   // single barrier/step (dbl-buffered staging)
  }
}

// ------------------------------------------- attention row @ eos + decode head
// O2 stored ENCODED (h+2): scores via qsum trick, att_z via sum(p)=1.
__global__ __launch_bounds__(256) void k_attn(
    const float* __restrict__ O2, const int* __restrict__ eos,
    const float* __restrict__ Wc, const float* __restrict__ bc,
    const float* __restrict__ Wd, const float* __restrict__ bd,
    float* __restrict__ out)
{
  const int b = blockIdx.x;
  const int tid = threadIdx.x;
  const int te = eos[b];
  __shared__ __align__(16) float q[DD];
  __shared__ float ps[LL];
  __shared__ float red[256];
  __shared__ __align__(16) float din[2 * DD];
  __shared__ __align__(16) float dvec[DD];
  const float* Ob = O2 + (long)b * LL * DD;
  const float4* Ob4 = (const float4*)Ob;

  float qpart = 0.f;
  for (int i = tid; i < DD; i += 256) {
    float v = Ob[(long)te * DD + i] - 2.0f;
    q[i] = v; qpart += v;
  }
  red[tid] = qpart; __syncthreads();
  for (int off = 128; off > 0; off >>= 1) {
    if (tid < off) red[tid] += red[tid + off];
    __syncthreads();
  }
  const float qsum = red[0];
  __syncthreads();
  const float4* q4 = (const float4*)q;

  for (int ss = tid; ss < LL; ss += 256) {
    float sc = -1.0e9f;
    if (ss < te) {
      float4 acc = {0.f, 0.f, 0.f, 0.f};
      for (int kq = 0; kq < 128; ++kq) {
        float4 o = Ob4[ss * 128 + kq];
        float4 qq = q4[kq];
        acc.x += o.x*qq.x; acc.y += o.y*qq.y; acc.z += o.z*qq.z; acc.w += o.w*qq.w;
      }
      sc = acc.x + acc.y + acc.z + acc.w - 2.0f * qsum;
    }
    ps[ss] = sc;
  }
  __syncthreads();
  float m = -3.0e38f;
  for (int ss = tid; ss < LL; ss += 256) m = fmaxf(m, ps[ss]);
  red[tid] = m; __syncthreads();
  for (int off = 128; off > 0; off >>= 1) {
    if (tid < off) red[tid] = fmaxf(red[tid], red[tid + off]);
    __syncthreads();
  }
  m = red[0]; __syncthreads();
  float lsum = 0.f;
  for (int ss = tid; ss < LL; ss += 256) {
    float e = expf(ps[ss] - m);
    ps[ss] = e; lsum += e;
  }
  __syncthreads();
  red[tid] = lsum; __syncthreads();
  for (int off = 128; off > 0; off >>= 1) {
    if (tid < off) red[tid] += red[tid + off];
    __syncthreads();
  }
  const float inv = 1.0f / red[0];
  __syncthreads();
  for (int ss = tid; ss < LL; ss += 256) ps[ss] *= inv;
  __syncthreads();

  if (tid < 128) {
    float4 acc = {0.f, 0.f, 0.f, 0.f};
    for (int ss = 0; ss < LL; ++ss) {
      float p = ps[ss];
      if (p != 0.0f) {
        float4 o = Ob4[ss * 128 + tid];
        acc.x += p*o.x; acc.y += p*o.y; acc.z += p*o.z; acc.w += p*o.w;
      }
    }
    acc.x -= 2.0f; acc.y -= 2.0f; acc.z -= 2.0f; acc.w -= 2.0f;
    ((float4*)din)[tid] = acc;
  } else {
    const int c = tid - 128;
    ((float4*)din)[128 + c] = q4[c];
  }
  __syncthreads();

  const float4* din4 = (const float4*)din;
  for (int jj = tid; jj < DD; jj += 256) {
    const float4* wrow = (const float4*)(Wc + (long)jj * 2 * DD);
    float4 acc = {0.f, 0.f, 0.f, 0.f};
    for (int iq = 0; iq < 256; ++iq) {
      float4 w = wrow[iq]; float4 d = din4[iq];
      acc.x += w.x*d.x; acc.y += w.y*d.y; acc.z += w.z*d.z; acc.w += w.w*d.w;
    }
    dvec[jj] = bc[jj] + acc.x + acc.y + acc.z + acc.w;
  }
  __syncthreads();

  if (tid < NCLS) {
    const float4* wrow = (const float4*)(Wd + (long)tid * DD);
    const float4* dv4 = (const float4*)dvec;
    float4 acc = {0.f, 0.f, 0.f, 0.f};
    for (int iq = 0; iq < 128; ++iq) {
      float4 w = wrow[iq]; float4 d = dv4[iq];
      acc.x += w.x*d.x; acc.y += w.y*d.y; acc.z += w.z*d.z; acc.w += w.w*d.w;
    }
    out[b * NCLS + tid] = bd[tid] + acc.x + acc.y + acc.z + acc.w;
  }
}

extern "C" void kernel_launch(void* const* d_in, const int* in_sizes, int n_in,
                              void* d_out, int out_size, void* d_ws, size_t ws_size,
                              hipStream_t stream)
{
  const int*   x    = (const int*)  d_in[0];
  const int*   eos  = (const int*)  d_in[1];
  const float* emb  = (const float*)d_in[2];
  const float* W_ih = (const float*)d_in[3];
  const float* W_hh = (const float*)d_in[4];
  const float* b_ih = (const float*)d_in[5];
  const float* b_hh = (const float*)d_in[6];
  const float* Wc   = (const float*)d_in[7];
  const float* bc   = (const float*)d_in[8];
  const float* Wd   = (const float*)d_in[9];
  const float* bd   = (const float*)d_in[10];
  float* out = (float*)d_out;

  // workspace: Abuf (h2+2) | Bbuf (xproj->h1+2). Poison 0xAA = -3e-13 < 1 => "not ready".
  float* Abuf = (float*)d_ws;
  float* Bbuf = Abuf + (size_t)NB * LL * DD;

  k_gemm_embed<<<2048, 256, 0, stream>>>(x, emb, W_ih, b_ih, b_hh, Bbuf);
  k_scan<<<256, 256, 0, stream>>>(W_ih, W_hh, b_ih, b_hh, Bbuf, Abuf);
  k_attn<<<NB, 256, 0, stream>>>(Abuf, eos, Wc, bc, Wd, bd, out);
}

// Round 6
// 3058.532 us; speedup vs baseline: 1.0086x; 1.0086x over previous
//
#include <hip/hip_runtime.h>
#include <hip/hip_bf16.h>
#include <cmath>

#define NB   16
#define LL   1024
#define DD   512
#define NCLS 64

// ---------------------------------------------- fused embed-gather + proj GEMM
__global__ __launch_bounds__(256) void k_gemm_embed(
    const int* __restrict__ x, const float* __restrict__ emb,
    const float* __restrict__ W, const float* __restrict__ b1,
    const float* __restrict__ b2, float* __restrict__ C)
{
  __shared__ __align__(16) float As[32][68];
  __shared__ __align__(16) float Ws[32][68];
  const int tid = threadIdx.x;
  const int n0 = (blockIdx.x & 7) * 64;
  const int m0 = (blockIdx.x >> 3) * 64;
  const int tm = tid & 15, tn = tid >> 4;
  float acc[4][4] = {};

  const int f0 = tid * 2, f1 = tid * 2 + 1;
  const int r0 = f0 >> 3, q0 = f0 & 7;
  const int r1 = f1 >> 3, q1 = f1 & 7;
  const long arow0 = (long)x[m0 + r0] * DD;
  const long arow1 = (long)x[m0 + r1] * DD;
  const long wrow0 = (long)(n0 + r0) * DD;
  const long wrow1 = (long)(n0 + r1) * DD;

  for (int k0 = 0; k0 < DD; k0 += 32) {
    float4 va = *(const float4*)(emb + arow0 + k0 + q0 * 4);
    float4 vb = *(const float4*)(emb + arow1 + k0 + q1 * 4);
    float4 wa = *(const float4*)(W + wrow0 + k0 + q0 * 4);
    float4 wb = *(const float4*)(W + wrow1 + k0 + q1 * 4);
    __syncthreads();
    As[q0*4+0][r0]=va.x; As[q0*4+1][r0]=va.y; As[q0*4+2][r0]=va.z; As[q0*4+3][r0]=va.w;
    As[q1*4+0][r1]=vb.x; As[q1*4+1][r1]=vb.y; As[q1*4+2][r1]=vb.z; As[q1*4+3][r1]=vb.w;
    Ws[q0*4+0][r0]=wa.x; Ws[q0*4+1][r0]=wa.y; Ws[q0*4+2][r0]=wa.z; Ws[q0*4+3][r0]=wa.w;
    Ws[q1*4+0][r1]=wb.x; Ws[q1*4+1][r1]=wb.y; Ws[q1*4+2][r1]=wb.z; Ws[q1*4+3][r1]=wb.w;
    __syncthreads();
    #pragma unroll
    for (int kk = 0; kk < 32; ++kk) {
      float4 a = *(const float4*)&As[kk][tm * 4];
      float4 w = *(const float4*)&Ws[kk][tn * 4];
      acc[0][0]+=a.x*w.x; acc[0][1]+=a.x*w.y; acc[0][2]+=a.x*w.z; acc[0][3]+=a.x*w.w;
      acc[1][0]+=a.y*w.x; acc[1][1]+=a.y*w.y; acc[1][2]+=a.y*w.z; acc[1][3]+=a.y*w.w;
      acc[2][0]+=a.z*w.x; acc[2][1]+=a.z*w.y; acc[2][2]+=a.z*w.z; acc[2][3]+=a.z*w.w;
      acc[3][0]+=a.w*w.x; acc[3][1]+=a.w*w.y; acc[3][2]+=a.w*w.z; acc[3][3]+=a.w*w.w;
    }
  }
  float bj[4];
  #pragma unroll
  for (int j = 0; j < 4; ++j)
    bj[j] = b1[n0 + tn * 4 + j] + b2[n0 + tn * 4 + j];
  #pragma unroll
  for (int i = 0; i < 4; ++i) {
    const int m = m0 + tm * 4 + i;
    float4 o = { acc[i][0]+bj[0], acc[i][1]+bj[1], acc[i][2]+bj[2], acc[i][3]+bj[3] };
    *(float4*)(C + (long)m * DD + n0 + tn * 4) = o;
  }
}

// ---------------------------------------------------------------- scan helpers
__device__ __forceinline__ float wave_red8(float y) {
  y += __int_as_float(__builtin_amdgcn_ds_swizzle(__float_as_int(y), 0x041F));
  y += __int_as_float(__builtin_amdgcn_ds_swizzle(__float_as_int(y), 0x081F));
  y += __int_as_float(__builtin_amdgcn_ds_swizzle(__float_as_int(y), 0x101F));
  return y;
}
__device__ __forceinline__ unsigned long long ald64(const float* p) {
  return __hip_atomic_load((const unsigned long long*)p, __ATOMIC_RELAXED,
                           __HIP_MEMORY_SCOPE_AGENT);
}
__device__ __forceinline__ void enc_st(float* p, float v) {
  __hip_atomic_store(p, v + 2.0f, __ATOMIC_RELAXED, __HIP_MEMORY_SCOPE_AGENT);
}
__device__ __forceinline__ float u64lo(unsigned long long u) {
  return __uint_as_float((unsigned)u);
}
__device__ __forceinline__ float u64hi(unsigned long long u) {
  return __uint_as_float((unsigned)(u >> 32));
}
// fast poll: sc0 = bypass L1, served by the XCD-shared L2 (~200-300 cy when
// producer is same-XCD). May return stale data -> only ACCEPTED when it shows
// the write-once "ready" encoding (>1), so staleness can only cost time.
__device__ __forceinline__ void ld2x16_sc0(const float* p, float4& a, float4& b) {
  asm volatile("global_load_dwordx4 %0, %2, off sc0\n\t"
               "global_load_dwordx4 %1, %2, off offset:16 sc0\n\t"
               "s_waitcnt vmcnt(0)"
               : "=v"(a), "=v"(b) : "v"(p) : "memory");
}
// slow poll: sc0 sc1 = agent-coherent (what __hip_atomic_load AGENT emits) —
// the guaranteed-progress path; identical semantics to r5's working spin.
__device__ __forceinline__ void ld2x16_agent(const float* p, float4& a, float4& b) {
  asm volatile("global_load_dwordx4 %0, %2, off sc0 sc1\n\t"
               "global_load_dwordx4 %1, %2, off offset:16 sc0 sc1\n\t"
               "s_waitcnt vmcnt(0)"
               : "=v"(a), "=v"(b) : "v"(p) : "memory");
}
__device__ __forceinline__ bool rdy8(const float4& a, const float4& b) {
  float m = fminf(fminf(fminf(a.x, a.y), fminf(a.z, a.w)),
                  fminf(fminf(b.x, b.y), fminf(b.z, b.w)));
  return m > 1.0f;
}
__device__ __forceinline__ float bl(unsigned u) { return __uint_as_float(u << 16); }
__device__ __forceinline__ float bh(unsigned u) { return __uint_as_float(u & 0xffff0000u); }
__device__ __forceinline__ unsigned short b16(float a) {
  __hip_bfloat16 h = __float2bfloat16(a);
  return *reinterpret_cast<unsigned short*>(&h);
}
__device__ __forceinline__ unsigned pk(float a, float b) {
  return (unsigned)b16(a) | ((unsigned)b16(b) << 16);
}
__device__ __forceinline__ float fast_tanh(float x) {
  float e = __expf(2.0f * x);
  return 1.0f - 2.0f / (e + 1.0f);
}
__device__ __forceinline__ float dot64_bf16(const uint4* Wp, int ctid, const float* hslice) {
  const float4* hp = (const float4*)hslice;
  float y0 = 0.f, y1 = 0.f, y2 = 0.f, y3 = 0.f;
  #pragma unroll
  for (int t4 = 0; t4 < 8; ++t4) {
    uint4 u = Wp[t4 * 128 + ctid];
    float4 ha = hp[2 * t4], hb = hp[2 * t4 + 1];
    y0 += bl(u.x) * ha.x; y1 += bh(u.x) * ha.y;
    y2 += bl(u.y) * ha.z; y3 += bh(u.y) * ha.w;
    y0 += bl(u.z) * hb.x; y1 += bh(u.z) * hb.y;
    y2 += bl(u.w) * hb.z; y3 += bh(u.w) * hb.w;
  }
  return (y0 + y1) + (y2 + y3);
}

// ------------------------------------------------- persistent 2-layer RNN scan
// 256 WGs = 32 row-groups x 8 batch-pairs; bp = g&7 so a batch-pair's 32 WGs
// share one XCD (heuristic only — correctness carried by the agent path).
// Spin = dual-path: sc0/L2 fast probe, agent/IF$ fallback.
__global__ __attribute__((amdgpu_flat_work_group_size(256, 256)))
__attribute__((amdgpu_waves_per_eu(1, 1)))
void k_scan(
    const float* __restrict__ W_ih, const float* __restrict__ W_hh,
    const float* __restrict__ b_ih, const float* __restrict__ b_hh,
    float* __restrict__ Bbuf,   // in: xproj layer1 -> h1+2 (in-place)
    float* __restrict__ Abuf)   // h2+2 (O2, encoded)
{
  const int g = blockIdx.x;
  const int bp = g & 7;
  const int rg = g >> 3;
  const int tid = threadIdx.x;
  const int bb = tid >> 7;
  const int rl = (tid >> 3) & 15;
  const int part = tid & 7;
  const int ctid = tid & 127;
  const int row = rg * 16 + rl;
  const int bmy = bp + 8 * bb;
  const bool leader = (part == 0);

  __shared__ __align__(16) float hS1[2][2][8 * 68];
  __shared__ __align__(16) float hS2[2][2][8 * 68];
  __shared__ uint4 W2P[8 * 128];
  __shared__ uint4 W3P[8 * 128];

  float w1[64];
  {
    const volatile float* p1 = W_hh + (long)row * DD + part * 64;
    #pragma unroll
    for (int q = 0; q < 64; ++q) w1[q] = p1[q];
  }
  if (tid < 128) {
    const int brow = rg * 16 + (ctid >> 3);
    const int bpart = ctid & 7;
    const float* p2 = W_ih + (long)DD * DD + (long)brow * DD + bpart * 64;
    const float* p3 = W_hh + (long)DD * DD + (long)brow * DD + bpart * 64;
    for (int t4 = 0; t4 < 8; ++t4) {
      uint4 u2, u3;
      u2.x = pk(p2[t4*8+0], p2[t4*8+1]); u2.y = pk(p2[t4*8+2], p2[t4*8+3]);
      u2.z = pk(p2[t4*8+4], p2[t4*8+5]); u2.w = pk(p2[t4*8+6], p2[t4*8+7]);
      u3.x = pk(p3[t4*8+0], p3[t4*8+1]); u3.y = pk(p3[t4*8+2], p3[t4*8+3]);
      u3.z = pk(p3[t4*8+4], p3[t4*8+5]); u3.w = pk(p3[t4*8+6], p3[t4*8+7]);
      W2P[t4 * 128 + ctid] = u2;
      W3P[t4 * 128 + ctid] = u3;
    }
  }
  const float bias2 = b_ih[DD + row] + b_hh[DD + row];
  float xin2_d1 = 0.f;

  float* Bb = Bbuf + (long)bmy * LL * DD;
  float* Ab = Abuf + (long)bmy * LL * DD;

  const int sel = tid >> 6;
  const int tl = tid & 63;
  float* psrcbase = ((sel < 2) ? Bbuf : Abuf) + (long)(bp + (sel & 1) * 8) * LL * DD;
  const int ldsw = (tl >> 3) * 68 + (tl & 7) * 8;

  float xpv = 0.f;
  if (leader) xpv = Bb[row];
  __syncthreads();

  for (int tau = 0; tau <= LL + 1; ++tau) {
    const int cur = tau & 1, nxt = cur ^ 1;

    // ---- M1: h1(tau) = tanh(xproj + w1 . h1(tau-1)) — critical chain ----
    if (tau < LL) {
      float y = 0.f;
      if (tau >= 1) {
        const float4* hp = (const float4*)&hS1[cur][bb][part * 68];
        float y0 = 0.f, y1 = 0.f, y2 = 0.f, y3 = 0.f;
        #pragma unroll
        for (int q = 0; q < 16; ++q) {
          float4 h4 = hp[q];
          y0 += w1[4*q+0] * h4.x; y1 += w1[4*q+1] * h4.y;
          y2 += w1[4*q+2] * h4.z; y3 += w1[4*q+3] * h4.w;
        }
        y = (y0 + y1) + (y2 + y3);
      }
      y = wave_red8(y);
      if (leader) enc_st(Bb + (long)tau * DD + row, fast_tanh(xpv + y));
    }

    // ---- early probes (agent 8B atomics, compiler-scheduled; checked late) ----
    const bool need = (sel < 2) ? (tau < LL) : (tau >= 2 && tau <= LL);
    const float* src = psrcbase + (long)((sel < 2) ? tau : ((tau - 2) < 0 ? 0 : (tau - 2))) * DD + tl * 8;
    unsigned long long u0 = 0, u1 = 0, u2 = 0, u3 = 0;
    if (need) { u0 = ald64(src); u1 = ald64(src + 2); u2 = ald64(src + 4); u3 = ald64(src + 6); }
    if (leader && tau + 1 < LL) xpv = Bb[(long)(tau + 1) * DD + row];

    // ---- M3 / M2 (latency hiding for the probes) ----
    if (tau >= 2) {
      float y = 0.f;
      if (tau >= 3) y = dot64_bf16(W3P, ctid, &hS2[cur][bb][part * 68]);
      y = wave_red8(y);
      if (leader) enc_st(Ab + (long)(tau - 2) * DD + row, fast_tanh(xin2_d1 + y));
    }
    if (tau >= 1 && tau <= LL) {
      float y = dot64_bf16(W2P, ctid, &hS1[cur][bb][part * 68]);
      y = wave_red8(y);
      xin2_d1 = y + bias2;
    }

    // ---- check probes; on miss, dual-path spin (L2 fast / IF$ guaranteed) ----
    if (need) {
      float* dst = ((sel < 2) ? &hS1[nxt][sel & 1][0] : &hS2[nxt][sel & 1][0]) + ldsw;
      float4 A = make_float4(u64lo(u0), u64hi(u0), u64lo(u1), u64hi(u1));
      float4 Bv = make_float4(u64lo(u2), u64hi(u2), u64lo(u3), u64hi(u3));
      if (!rdy8(A, Bv)) {
        for (;;) {
          ld2x16_sc0(src, A, Bv);          // ~L2 latency when same-XCD producer
          if (rdy8(A, Bv)) break;
          ld2x16_agent(src, A, Bv);        // coherence-point fallback
          if (rdy8(A, Bv)) break;
        }
      }
      ((float4*)dst)[0] = make_float4(A.x - 2.f, A.y - 2.f, A.z - 2.f, A.w - 2.f);
      ((float4*)dst)[1] = make_float4(Bv.x - 2.f, Bv.y - 2.f, Bv.z - 2.f, Bv.w - 2.f);
    }
    __syncthreads();
  }
}

// ------------------------------------------- attention row @ eos + decode head
__global__ __launch_bounds__(256) void k_attn(
    const float* __restrict__ O2, const int* __restrict__ eos,
    const float* __restrict__ Wc, const float* __restrict__ bc,
    const float* __restrict__ Wd, const float* __restrict__ bd,
    float* __restrict__ out)
{
  const int b = blockIdx.x;
  const int tid = threadIdx.x;
  const int te = eos[b];
  __shared__ __align__(16) float q[DD];
  __shared__ float ps[LL];
  __shared__ float red[256];
  __shared__ __align__(16) float din[2 * DD];
  __shared__ __align__(16) float dvec[DD];
  const float* Ob = O2 + (long)b * LL * DD;
  const float4* Ob4 = (const float4*)Ob;

  float qpart = 0.f;
  for (int i = tid; i < DD; i += 256) {
    float v = Ob[(long)te * DD + i] - 2.0f;
    q[i] = v; qpart += v;
  }
  red[tid] = qpart; __syncthreads();
  for (int off = 128; off > 0; off >>= 1) {
    if (tid < off) red[tid] += red[tid + off];
    __syncthreads();
  }
  const float qsum = red[0];
  __syncthreads();
  const float4* q4 = (const float4*)q;

  for (int ss = tid; ss < LL; ss += 256) {
    float sc = -1.0e9f;
    if (ss < te) {
      float4 acc = {0.f, 0.f, 0.f, 0.f};
      for (int kq = 0; kq < 128; ++kq) {
        float4 o = Ob4[ss * 128 + kq];
        float4 qq = q4[kq];
        acc.x += o.x*qq.x; acc.y += o.y*qq.y; acc.z += o.z*qq.z; acc.w += o.w*qq.w;
      }
      sc = acc.x + acc.y + acc.z + acc.w - 2.0f * qsum;
    }
    ps[ss] = sc;
  }
  __syncthreads();
  float m = -3.0e38f;
  for (int ss = tid; ss < LL; ss += 256) m = fmaxf(m, ps[ss]);
  red[tid] = m; __syncthreads();
  for (int off = 128; off > 0; off >>= 1) {
    if (tid < off) red[tid] = fmaxf(red[tid], red[tid + off]);
    __syncthreads();
  }
  m = red[0]; __syncthreads();
  float lsum = 0.f;
  for (int ss = tid; ss < LL; ss += 256) {
    float e = expf(ps[ss] - m);
    ps[ss] = e; lsum += e;
  }
  __syncthreads();
  red[tid] = lsum; __syncthreads();
  for (int off = 128; off > 0; off >>= 1) {
    if (tid < off) red[tid] += red[tid + off];
    __syncthreads();
  }
  const float inv = 1.0f / red[0];
  __syncthreads();
  for (int ss = tid; ss < LL; ss += 256) ps[ss] *= inv;
  __syncthreads();

  if (tid < 128) {
    float4 acc = {0.f, 0.f, 0.f, 0.f};
    for (int ss = 0; ss < LL; ++ss) {
      float p = ps[ss];
      if (p != 0.0f) {
        float4 o = Ob4[ss * 128 + tid];
        acc.x += p*o.x; acc.y += p*o.y; acc.z += p*o.z; acc.w += p*o.w;
      }
    }
    acc.x -= 2.0f; acc.y -= 2.0f; acc.z -= 2.0f; acc.w -= 2.0f;
    ((float4*)din)[tid] = acc;
  } else {
    const int c = tid - 128;
    ((float4*)din)[128 + c] = q4[c];
  }
  __syncthreads();

  const float4* din4 = (const float4*)din;
  for (int jj = tid; jj < DD; jj += 256) {
    const float4* wrow = (const float4*)(Wc + (long)jj * 2 * DD);
    float4 acc = {0.f, 0.f, 0.f, 0.f};
    for (int iq = 0; iq < 256; ++iq) {
      float4 w = wrow[iq]; float4 d = din4[iq];
      acc.x += w.x*d.x; acc.y += w.y*d.y; acc.z += w.z*d.z; acc.w += w.w*d.w;
    }
    dvec[jj] = bc[jj] + acc.x + acc.y + acc.z + acc.w;
  }
  __syncthreads();

  if (tid < NCLS) {
    const float4* wrow = (const float4*)(Wd + (long)tid * DD);
    const float4* dv4 = (const float4*)dvec;
    float4 acc = {0.f, 0.f, 0.f, 0.f};
    for (int iq = 0; iq < 128; ++iq) {
      float4 w = wrow[iq]; float4 d = dv4[iq];
      acc.x += w.x*d.x; acc.y += w.y*d.y; acc.z += w.z*d.z; acc.w += w.w*d.w;
    }
    out[b * NCLS + tid] = bd[tid] + acc.x + acc.y + acc.z + acc.w;
  }
}

extern "C" void kernel_launch(void* const* d_in, const int* in_sizes, int n_in,
                              void* d_out, int out_size, void* d_ws, size_t ws_size,
                              hipStream_t stream)
{
  const int*   x    = (const int*)  d_in[0];
  const int*   eos  = (const int*)  d_in[1];
  const float* emb  = (const float*)d_in[2];
  const float* W_ih = (const float*)d_in[3];
  const float* W_hh = (const float*)d_in[4];
  const float* b_ih = (const float*)d_in[5];
  const float* b_hh = (const float*)d_in[6];
  const float* Wc   = (const float*)d_in[7];
  const float* bc   = (const float*)d_in[8];
  const float* Wd   = (const float*)d_in[9];
  const float* bd   = (const float*)d_in[10];
  float* out = (float*)d_out;

  float* Abuf = (float*)d_ws;
  float* Bbuf = Abuf + (size_t)NB * LL * DD;

  k_gemm_embed<<<2048, 256, 0, stream>>>(x, emb, W_ih, b_ih, b_hh, Bbuf);
  k_scan<<<256, 256, 0, stream>>>(W_ih, W_hh, b_ih, b_hh, Bbuf, Abuf);
  k_attn<<<NB, 256, 0, stream>>>(Abuf, eos, Wc, bc, Wd, bd, out);
}